// Round 4
// baseline (737.912 us; speedup 1.0000x reference)
//
#include <hip/hip_runtime.h>
#include <hip/hip_bf16.h>
#include <math.h>

#define DEV_INLINE __device__ __forceinline__

typedef __attribute__((ext_vector_type(8))) short short8;
typedef __attribute__((ext_vector_type(4))) float f32x4;

constexpr int H = 128, W = 128, C = 128, B = 4;
constexpr int HWc = H * W;        // 16384
constexpr int KK = 9;
constexpr int KT2 = 1184;         // 37 chunks * 32

DEV_INLINE unsigned short f2bf(float f) {
  union { float f; unsigned u; } v; v.f = f;
  unsigned r = v.u + 0x7FFFu + ((v.u >> 16) & 1u);   // RNE
  return (unsigned short)(r >> 16);
}
DEV_INLINE float bf2f(unsigned short u) {
  union { unsigned u; float f; } v; v.u = ((unsigned)u) << 16;
  return v.f;
}
DEV_INLINE unsigned pack2bf(float a, float b) {
  float2 t; t.x = a; t.y = b;
  __hip_bfloat162 h = __float22bfloat162_rn(t);      // RNE, 1 HW instr on gfx950
  union { __hip_bfloat162 h; unsigned u; } c; c.h = h;
  return c.u;
}

// One wave (64 threads) per block; wave owns 16 positions (one row segment).
// K order: chunk ch = cg*9 + tap, k-in-chunk = q*8+j -> channel cg*32+q*8+j.
// B fragment built directly in registers: lane (m16,q) gathers 8 channels at
// position hx0+m16 (4 bilinear corners from table). A fragment loaded straight
// from global weight table (L1-hot, same stream for all waves). NO barriers in
// the K-loop -> waves fully independent, gathers overlap MFMAs.
// Grid: 4096 blocks; blk&7 -> XCD stripe (b, 64-row band) as in R3.
// MODE 0: plain conv O=32 (18 offs + 9 mask + 5 pad). MODE 1: deform O=128,
// PReLU -> bf16. MODE 2: deform O=128, BN2 + fp32 residual -> fp32.
template<int MODE, bool BN>
__global__ __launch_bounds__(64, 4)
void gemm3(const unsigned short* __restrict__ src,      // bf16 (B,C,H,W)
           const unsigned short* __restrict__ wT,       // [O][1184] bf16
           const float* __restrict__ offs,
           const float* __restrict__ msk,
           const float* __restrict__ pA, const float* __restrict__ pB,
           const float* __restrict__ pM, const float* __restrict__ pV,
           const float* __restrict__ resid,
           float* __restrict__ outf,
           unsigned short* __restrict__ outh,
           float* __restrict__ out1)
{
  constexpr int O  = (MODE == 0) ? 32 : 128;
  constexpr int NT = O / 16;
  __shared__ ushort4 sIdx[(MODE != 0) ? KK * 16 : 1];   // [tap][pp]
  __shared__ float4  sWtb[(MODE != 0) ? KK * 16 : 1];

  const int lane = threadIdx.x;
  const int raw  = blockIdx.x;
  const int xcd  = raw & 7;
  const int slot = raw >> 3;                 // [0,512)
  const int b    = xcd >> 1;
  const int hy   = ((xcd & 1) << 6) | (slot >> 3);
  const int hx0  = (slot & 7) << 4;
  const unsigned short* __restrict__ srcB = src + (size_t)b * C * HWc;

  // ---- bilinear table: 9 taps x 16 positions, built by the wave ----
  if constexpr (MODE != 0) {
    for (int e = lane; e < KK * 16; e += 64) {
      const int tap = e >> 4;
      const int hx  = hx0 + (e & 15);
      const int ky  = tap / 3, kx = tap - 3 * (tap / 3);
      const size_t ob = ((size_t)(b * 18 + 2 * tap) * H + hy) * W + hx;
      const float oy = offs[ob];
      const float ox = offs[ob + (size_t)HWc];
      const float mv = msk[((size_t)(b * 9 + tap) * H + hy) * W + hx];
      const float py = (float)(hy - 1 + ky) + oy;
      const float px = (float)(hx - 1 + kx) + ox;
      const float fy = floorf(py), fx = floorf(px);
      const float ay = py - fy, ax = px - fx;
      const int y0 = (int)fy, x0 = (int)fx;
      const int y1 = y0 + 1, x1 = x0 + 1;
      const bool vy0 = (unsigned)y0 < (unsigned)H, vy1 = (unsigned)y1 < (unsigned)H;
      const bool vx0 = (unsigned)x0 < (unsigned)W, vx1 = (unsigned)x1 < (unsigned)W;
      const int y0c = min(max(y0, 0), H - 1), y1c = min(max(y1, 0), H - 1);
      const int x0c = min(max(x0, 0), W - 1), x1c = min(max(x1, 0), W - 1);
      sIdx[e] = make_ushort4((unsigned short)(y0c * W + x0c),
                             (unsigned short)(y0c * W + x1c),
                             (unsigned short)(y1c * W + x0c),
                             (unsigned short)(y1c * W + x1c));
      const float wy0 = 1.f - ay, wx0 = 1.f - ax;
      sWtb[e] = make_float4(wy0 * wx0 * ((vy0 && vx0) ? mv : 0.f),
                            wy0 * ax  * ((vy0 && vx1) ? mv : 0.f),
                            ay  * wx0 * ((vy1 && vx0) ? mv : 0.f),
                            ay  * ax  * ((vy1 && vx1) ? mv : 0.f));
    }
    __syncthreads();   // single-wave block: near-free
  }

  f32x4 acc[NT];
  #pragma unroll
  for (int i = 0; i < NT; ++i) acc[i] = (f32x4){0.f, 0.f, 0.f, 0.f};

  const int m16 = lane & 15;
  const int q   = lane >> 4;
  const int hx  = hx0 + m16;
  const unsigned short* __restrict__ aBase = wT + (size_t)m16 * KT2 + (q << 3);

  int ch = 0;
  for (int cg = 0; cg < 4; ++cg) {
    const unsigned short* __restrict__ pl = srcB + (size_t)((cg << 5) + (q << 3)) * HWc;
    for (int tap = 0; tap < 9; ++tap, ++ch) {
      // ---- B fragment in registers ----
      union { unsigned u[4]; short8 s; } bfr;
      if constexpr (MODE != 0) {
        const int e = (tap << 4) + m16;
        const ushort4 id = sIdx[e];
        const float4  wt = sWtb[e];
        float sv[8];
        #pragma unroll
        for (int j = 0; j < 8; ++j) {
          const unsigned short* qp = pl + (size_t)j * HWc;
          sv[j] = wt.x * bf2f(qp[id.x]) + wt.y * bf2f(qp[id.y])
                + wt.z * bf2f(qp[id.z]) + wt.w * bf2f(qp[id.w]);
        }
        #pragma unroll
        for (int t = 0; t < 4; ++t) bfr.u[t] = pack2bf(sv[2 * t], sv[2 * t + 1]);
      } else {
        const int ky = tap / 3, kx = tap - 3 * (tap / 3);
        const int iy = hy + ky - 1;
        const int ix = hx + kx - 1;
        const bool vok = ((unsigned)iy < (unsigned)H) && ((unsigned)ix < (unsigned)W);
        const unsigned short* qp = pl + (iy * W + ix);
        #pragma unroll
        for (int t = 0; t < 4; ++t) {
          const unsigned short lo = vok ? qp[(size_t)(2 * t) * HWc]     : (unsigned short)0;
          const unsigned short hi = vok ? qp[(size_t)(2 * t + 1) * HWc] : (unsigned short)0;
          bfr.u[t] = (unsigned)lo | ((unsigned)hi << 16);
        }
      }
      // ---- MFMA: A straight from global (L1-hot) ----
      const unsigned short* ap = aBase + ch * 32;
      #pragma unroll
      for (int ot = 0; ot < NT; ++ot) {
        const short8 afr = *(const short8*)(ap + (size_t)(ot * 16) * KT2);
        acc[ot] = __builtin_amdgcn_mfma_f32_16x16x32_bf16(afr, bfr.s, acc[ot], 0, 0, 0);
      }
    }
  }
  if constexpr (BN) {   // BN-shift chunk (ch == 36)
    union { unsigned u[4]; short8 s; } bfr;
    float sv[8];
    #pragma unroll
    for (int j = 0; j < 8; ++j) {
      const int kj = (q << 3) + j;
      float s = 0.f;
      if (kj < KK) {
        if constexpr (MODE != 0) {
          const float4 wt = sWtb[(kj << 4) + m16];
          s = wt.x + wt.y + wt.z + wt.w;
        } else {
          const int ky = kj / 3, kx = kj - 3 * (kj / 3);
          const int iy = hy + ky - 1, ix = hx + kx - 1;
          s = (((unsigned)iy < (unsigned)H) && ((unsigned)ix < (unsigned)W)) ? 1.f : 0.f;
        }
      }
      sv[j] = s;
    }
    #pragma unroll
    for (int t = 0; t < 4; ++t) bfr.u[t] = pack2bf(sv[2 * t], sv[2 * t + 1]);
    const unsigned short* ap = aBase + 36 * 32;
    #pragma unroll
    for (int ot = 0; ot < NT; ++ot) {
      const short8 afr = *(const short8*)(ap + (size_t)(ot * 16) * KT2);
      acc[ot] = __builtin_amdgcn_mfma_f32_16x16x32_bf16(afr, bfr.s, acc[ot], 0, 0, 0);
    }
  }

  // ---- epilogue: D col = m16 -> position, row = q*4+rg -> o ----
  #pragma unroll
  for (int ot = 0; ot < NT; ++ot) {
    #pragma unroll
    for (int rg = 0; rg < 4; ++rg) {
      const int o = ot * 16 + (q << 2) + rg;
      const float vv = acc[ot][rg];
      if constexpr (MODE == 0) {
        if (o < 18) {
          outf[((size_t)(b * 18 + o) * H + hy) * W + hx] = vv + pA[o];
        } else if (o < 27) {
          const float z = vv + pA[o];
          out1[((size_t)(b * 9 + (o - 18)) * H + hy) * W + hx] = 2.f / (1.f + expf(-z));
        }
      } else if constexpr (MODE == 1) {
        const size_t oi = ((size_t)(b * C + o) * H + hy) * W + hx;
        const float a = pA[o];
        outh[oi] = f2bf(vv > 0.f ? vv : a * vv);
      } else {
        const size_t oi = ((size_t)(b * C + o) * H + hy) * W + hx;
        const float s  = pA[o] * rsqrtf(pV[o] + 1e-5f);
        const float sh = pB[o] - pM[o] * s;
        outf[oi] = vv * s + sh + resid[oi];
      }
    }
  }
}

__global__ void xcvt(const float* __restrict__ x, unsigned short* __restrict__ xb)
{
  const int i = blockIdx.x * 256 + threadIdx.x;
  const float4 v = ((const float4*)x)[i];
  ushort4 o;
  o.x = f2bf(v.x); o.y = f2bf(v.y); o.z = f2bf(v.z); o.w = f2bf(v.w);
  *(ushort4*)(xb + (size_t)i * 4) = o;
}

__global__ void prep2(const float* __restrict__ w1, const float* __restrict__ w2,
                      const float* __restrict__ ow1, const float* __restrict__ mw1,
                      const float* __restrict__ ob1, const float* __restrict__ mb1,
                      const float* __restrict__ ow2, const float* __restrict__ mw2,
                      const float* __restrict__ ob2, const float* __restrict__ mb2,
                      const float* __restrict__ g, const float* __restrict__ bb,
                      const float* __restrict__ m, const float* __restrict__ v,
                      unsigned short* __restrict__ wb1, unsigned short* __restrict__ wb2,
                      unsigned short* __restrict__ wom1, unsigned short* __restrict__ wom2,
                      float* __restrict__ bias1, float* __restrict__ bias2)
{
  const int i = blockIdx.x * 256 + threadIdx.x;
  if (i < 128 * KT2) {
    const int o = i / KT2, kp = i - o * KT2;
    unsigned short v1 = 0, v2 = 0;
    if (kp < 1152) {
      const int chn = kp >> 5, j = kp & 31;
      const int cg = chn / 9, tap = chn - 9 * cg;
      const int c = (cg << 5) + j;
      const float s = g[c] * rsqrtf(v[c] + 1e-5f);
      v1 = f2bf(w1[(size_t)(o * 128 + c) * 9 + tap] * s);
      v2 = f2bf(w2[(size_t)(o * 128 + c) * 9 + tap]);
    } else if (kp < 1152 + KK) {
      const int kk = kp - 1152;
      float acc = 0.f;
      for (int c = 0; c < 128; ++c) {
        const float s  = g[c] * rsqrtf(v[c] + 1e-5f);
        const float sh = bb[c] - m[c] * s;
        acc += w1[(size_t)(o * 128 + c) * 9 + kk] * sh;
      }
      v1 = f2bf(acc);
    }
    wb1[i] = v1; wb2[i] = v2;
  }
  if (i < 32 * KT2) {
    const int o = i / KT2, kp = i - o * KT2;
    unsigned short v1 = 0, v2 = 0;
    if (kp < 1152) {
      const int chn = kp >> 5, j = kp & 31;
      const int cg = chn / 9, tap = chn - 9 * cg;
      const int c = (cg << 5) + j;
      const float s = g[c] * rsqrtf(v[c] + 1e-5f);
      if (o < 18) {
        v1 = f2bf(ow1[(size_t)(o * 128 + c) * 9 + tap] * s);
        v2 = f2bf(ow2[(size_t)(o * 128 + c) * 9 + tap]);
      } else if (o < 27) {
        v1 = f2bf(mw1[(size_t)((o - 18) * 128 + c) * 9 + tap] * s);
        v2 = f2bf(mw2[(size_t)((o - 18) * 128 + c) * 9 + tap]);
      }
    } else if (kp < 1152 + KK && o < 27) {
      const int kk = kp - 1152;
      const float* wsrc = (o < 18) ? ow1 + (size_t)o * 1152
                                   : mw1 + (size_t)(o - 18) * 1152;
      float acc = 0.f;
      for (int c = 0; c < 128; ++c) {
        const float s  = g[c] * rsqrtf(v[c] + 1e-5f);
        const float sh = bb[c] - m[c] * s;
        acc += wsrc[(size_t)c * 9 + kk] * sh;
      }
      v1 = f2bf(acc);
    }
    wom1[i] = v1; wom2[i] = v2;
  }
  if (i < 32) {
    float b1 = 0.f, b2 = 0.f;
    if (i < 18)      { b1 = ob1[i];      b2 = ob2[i]; }
    else if (i < 27) { b1 = mb1[i - 18]; b2 = mb2[i - 18]; }
    bias1[i] = b1; bias2[i] = b2;
  }
}

extern "C" void kernel_launch(void* const* d_in, const int* in_sizes, int n_in,
                              void* d_out, int out_size, void* d_ws, size_t ws_size,
                              hipStream_t stream)
{
  const float* x     = (const float*)d_in[0];
  const float* bn1g  = (const float*)d_in[1];
  const float* bn1b  = (const float*)d_in[2];
  const float* bn1m  = (const float*)d_in[3];
  const float* bn1v  = (const float*)d_in[4];
  const float* ow1   = (const float*)d_in[5];
  const float* ob1   = (const float*)d_in[6];
  const float* mw1   = (const float*)d_in[7];
  const float* mb1   = (const float*)d_in[8];
  const float* w1    = (const float*)d_in[9];
  const float* alpha = (const float*)d_in[10];
  const float* ow2   = (const float*)d_in[11];
  const float* ob2   = (const float*)d_in[12];
  const float* mw2   = (const float*)d_in[13];
  const float* mb2   = (const float*)d_in[14];
  const float* w2    = (const float*)d_in[15];
  const float* bn2g  = (const float*)d_in[16];
  const float* bn2b  = (const float*)d_in[17];
  const float* bn2m  = (const float*)d_in[18];
  const float* bn2v  = (const float*)d_in[19];
  float* out = (float*)d_out;

  char* wsp = (char*)d_ws;
  unsigned short* xbf  = (unsigned short*)(wsp);             // 16777216 B
  unsigned short* r2bf = (unsigned short*)(wsp + 16777216);  // 16777216 B
  float* offb = (float*)(wsp + 33554432);                    // 4718592 B
  float* mskb = (float*)(wsp + 38273024);                    // 2359296 B
  unsigned short* wb1  = (unsigned short*)(wsp + 40632320);  // 303104 B
  unsigned short* wb2  = (unsigned short*)(wsp + 40935424);  // 303104 B
  unsigned short* wom1 = (unsigned short*)(wsp + 41238528);  // 75776 B
  unsigned short* wom2 = (unsigned short*)(wsp + 41314304);  // 75776 B
  float* bias1 = (float*)(wsp + 41390080);
  float* bias2 = (float*)(wsp + 41390208);

  xcvt<<<8192, 256, 0, stream>>>(x, xbf);
  prep2<<<(128 * KT2 + 255) / 256, 256, 0, stream>>>(
      w1, w2, ow1, mw1, ob1, mb1, ow2, mw2, ob2, mb2,
      bn1g, bn1b, bn1m, bn1v, wb1, wb2, wom1, wom2, bias1, bias2);

  dim3 grid(4096);
  dim3 blk(64);
  gemm3<0, true><<<grid, blk, 0, stream>>>(xbf, wom1, nullptr, nullptr, bias1,
      nullptr, nullptr, nullptr, nullptr, offb, nullptr, mskb);
  gemm3<1, true><<<grid, blk, 0, stream>>>(xbf, wb1, offb, mskb, alpha,
      nullptr, nullptr, nullptr, nullptr, nullptr, r2bf, nullptr);
  gemm3<0, false><<<grid, blk, 0, stream>>>(r2bf, wom2, nullptr, nullptr, bias2,
      nullptr, nullptr, nullptr, nullptr, offb, nullptr, mskb);
  gemm3<2, false><<<grid, blk, 0, stream>>>(r2bf, wb2, offb, mskb, bn2g,
      bn2b, bn2m, bn2v, x, out, nullptr, nullptr);
}

// Round 5
// 469.440 us; speedup vs baseline: 1.5719x; 1.5719x over previous
//
#include <hip/hip_runtime.h>
#include <hip/hip_bf16.h>
#include <math.h>

#define DEV_INLINE __device__ __forceinline__

typedef __attribute__((ext_vector_type(8))) short short8;
typedef __attribute__((ext_vector_type(4))) float f32x4;

constexpr int H = 128, W = 128, C = 128, B = 4;
constexpr int HWc = H * W;        // 16384
constexpr int KK = 9;
constexpr int KT2 = 1184;         // 37 chunks * 32

DEV_INLINE unsigned short f2bf(float f) {
  union { float f; unsigned u; } v; v.f = f;
  unsigned r = v.u + 0x7FFFu + ((v.u >> 16) & 1u);   // RNE
  return (unsigned short)(r >> 16);
}
DEV_INLINE float ubits(unsigned u) {
  union { unsigned u; float f; } v; v.u = u; return v.f;
}
DEV_INLINE unsigned pack2bf(float a, float b) {
  float2 t; t.x = a; t.y = b;
  __hip_bfloat162 h = __float22bfloat162_rn(t);
  union { __hip_bfloat162 h; unsigned u; } c; c.h = h;
  return c.u;
}

// Block = 256 thr (4 waves) over 16 positions. K-split x4: wave wv owns
// channel-group wv (chunks wv*9..wv*9+8; chunk = 32 channels x 1 tap).
// Gathers: per sample 2 unaligned-dword row-pair loads (corners share a
// dword); per-tap table holds clamped row-base pair + 4 folded weights.
// Weights pre-swizzled wS[ch][NT][64][8] -> fully coalesced A loads.
// fp32 partial accs reduced via LDS (waves 1-3 write, wave 0 adds+epilogue).
// Grid 4096; blk&7 -> XCD stripe. MODE 0: plain conv O=32. MODE 1: deform
// O=128 PReLU->bf16. MODE 2: deform O=128 BN2+residual->fp32.
template<int MODE, bool BN>
__global__ __launch_bounds__(256, 5)
void gemm5(const unsigned short* __restrict__ src,     // bf16 (B,C,H,W)
           const unsigned short* __restrict__ wS,      // swizzled [37][NT][64][8]
           const float* __restrict__ offs,
           const float* __restrict__ msk,
           const float* __restrict__ pA, const float* __restrict__ pB,
           const float* __restrict__ pM, const float* __restrict__ pV,
           const float* __restrict__ resid,
           float* __restrict__ outf,
           unsigned short* __restrict__ outh,
           float* __restrict__ out1)
{
  constexpr int O  = (MODE == 0) ? 32 : 128;
  constexpr int NT = O / 16;
  __shared__ ushort2 sId[(MODE != 0) ? KK * 16 : 1];
  __shared__ float4  sWt[(MODE != 0) ? KK * 16 : 1];
  __shared__ float   red[3 * NT * 4 * 64];

  const int tid  = threadIdx.x;
  const int lane = tid & 63;
  const int m16  = lane & 15;
  const int q    = lane >> 4;
  const int wv   = tid >> 6;

  const int raw  = blockIdx.x;
  const int xcd  = raw & 7;
  const int slot = raw >> 3;                // [0,512)
  const int b    = xcd >> 1;
  const int hy   = ((xcd & 1) << 6) | (slot >> 3);
  const int hx0  = (slot & 7) << 4;
  const unsigned short* __restrict__ srcB = src + (size_t)b * C * HWc;

  // ---- bilinear row-pair table: 9 taps x 16 positions ----
  if constexpr (MODE != 0) {
    if (tid < KK * 16) {
      const int tap = tid >> 4;
      const int hx  = hx0 + (tid & 15);
      const int ky  = tap / 3, kx = tap - 3 * (tap / 3);
      const size_t ob = ((size_t)(b * 18 + 2 * tap) * H + hy) * W + hx;
      const float oy = offs[ob];
      const float ox = offs[ob + (size_t)HWc];
      const float mv = msk[((size_t)(b * 9 + tap) * H + hy) * W + hx];
      const float py = (float)(hy - 1 + ky) + oy;
      const float px = (float)(hx - 1 + kx) + ox;
      const float fy = floorf(py), fx = floorf(px);
      const float ay = py - fy, ax = px - fx;
      const int y0 = (int)fy, x0 = (int)fx;
      const int y1 = y0 + 1, x1 = x0 + 1;
      const float wyt = (1.f - ay) * (((unsigned)y0 < (unsigned)H) ? 1.f : 0.f);
      const float wyb = ay * (((unsigned)y1 < (unsigned)H) ? 1.f : 0.f);
      const int y0c = min(max(y0, 0), H - 1), y1c = min(max(y1, 0), H - 1);
      const int bx  = min(max(x0, 0), W - 2);
      float wA = 0.f, wB = 0.f;
      if (x0 == bx)          { wA = 1.f - ax; wB = ax; }   // interior: x1=bx+1<=127
      else if (x1 == bx)     { wA = ax; }                  // x0 == -1
      else if (x0 == bx + 1) { wB = 1.f - ax; }            // x0 == 127
      sId[tid] = make_ushort2((unsigned short)(y0c * W + bx),
                              (unsigned short)(y1c * W + bx));
      sWt[tid] = make_float4(mv * wyt * wA, mv * wyt * wB,
                             mv * wyb * wA, mv * wyb * wB);
    }
    __syncthreads();
  }

  f32x4 acc[NT];
  #pragma unroll
  for (int i = 0; i < NT; ++i) acc[i] = (f32x4){0.f, 0.f, 0.f, 0.f};

  const int hx = hx0 + m16;
  const unsigned short* __restrict__ pl =
      srcB + (size_t)((wv << 5) + (q << 3)) * HWc;

  for (int tap = 0; tap < 9; ++tap) {
    union { unsigned u[4]; short8 s; } bfr;
    if constexpr (MODE != 0) {
      const int e = (tap << 4) + m16;
      const ushort2 id = sId[e];
      const float4  wt = sWt[e];
      float sv[8];
      #pragma unroll
      for (int j = 0; j < 8; ++j) {
        const unsigned short* qp = pl + (size_t)j * HWc;
        unsigned a, c;
        __builtin_memcpy(&a, qp + id.x, 4);   // {v[bx], v[bx+1]} row y0
        __builtin_memcpy(&c, qp + id.y, 4);   // row y1
        sv[j] = wt.x * ubits(a << 16) + wt.y * ubits(a & 0xFFFF0000u)
              + wt.z * ubits(c << 16) + wt.w * ubits(c & 0xFFFF0000u);
      }
      #pragma unroll
      for (int t = 0; t < 4; ++t) bfr.u[t] = pack2bf(sv[2 * t], sv[2 * t + 1]);
    } else {
      const int ky = tap / 3, kx = tap - 3 * (tap / 3);
      const int iy = hy + ky - 1;
      const int ix = hx + kx - 1;
      const bool vok = ((unsigned)iy < (unsigned)H) && ((unsigned)ix < (unsigned)W);
      const unsigned short* qp = pl + (iy * W + ix);
      #pragma unroll
      for (int t = 0; t < 4; ++t) {
        const unsigned short lo = vok ? qp[(size_t)(2 * t) * HWc]     : (unsigned short)0;
        const unsigned short hi = vok ? qp[(size_t)(2 * t + 1) * HWc] : (unsigned short)0;
        bfr.u[t] = (unsigned)lo | ((unsigned)hi << 16);
      }
    }
    const int ch = wv * 9 + tap;
    const unsigned short* ap = wS + ((size_t)ch * NT * 64 + lane) * 8;
    #pragma unroll
    for (int ot = 0; ot < NT; ++ot) {
      const short8 afr = *(const short8*)(ap + (size_t)ot * 512);
      acc[ot] = __builtin_amdgcn_mfma_f32_16x16x32_bf16(afr, bfr.s, acc[ot], 0, 0, 0);
    }
  }

  if constexpr (BN) {
    if (wv == 3) {          // BN-shift chunk (ch 36)
      union { unsigned u[4]; short8 s; } bfr;
      float sv[8];
      #pragma unroll
      for (int j = 0; j < 8; ++j) {
        const int kj = (q << 3) + j;
        float s = 0.f;
        if (kj < KK) {
          if constexpr (MODE != 0) {
            const float4 wt = sWt[(kj << 4) + m16];
            s = wt.x + wt.y + wt.z + wt.w;
          } else {
            const int ky = kj / 3, kx = kj - 3 * (kj / 3);
            const int iy = hy + ky - 1, ix = hx + kx - 1;
            s = (((unsigned)iy < (unsigned)H) && ((unsigned)ix < (unsigned)W)) ? 1.f : 0.f;
          }
        }
        sv[j] = s;
      }
      #pragma unroll
      for (int t = 0; t < 4; ++t) bfr.u[t] = pack2bf(sv[2 * t], sv[2 * t + 1]);
      const unsigned short* ap = wS + ((size_t)36 * NT * 64 + lane) * 8;
      #pragma unroll
      for (int ot = 0; ot < NT; ++ot) {
        const short8 afr = *(const short8*)(ap + (size_t)ot * 512);
        acc[ot] = __builtin_amdgcn_mfma_f32_16x16x32_bf16(afr, bfr.s, acc[ot], 0, 0, 0);
      }
    }
  }

  // ---- K-split reduction ----
  if (wv != 0) {
    float* r = red + (size_t)(wv - 1) * (NT * 256);
    #pragma unroll
    for (int ot = 0; ot < NT; ++ot)
      #pragma unroll
      for (int rg = 0; rg < 4; ++rg)
        r[(ot * 4 + rg) * 64 + lane] = acc[ot][rg];
  }
  __syncthreads();
  if (wv == 0) {
    #pragma unroll
    for (int ot = 0; ot < NT; ++ot) {
      #pragma unroll
      for (int rg = 0; rg < 4; ++rg) {
        const int idx = (ot * 4 + rg) * 64 + lane;
        const float vv = acc[ot][rg] + red[idx]
                       + red[NT * 256 + idx] + red[2 * NT * 256 + idx];
        const int o = ot * 16 + (q << 2) + rg;
        if constexpr (MODE == 0) {
          if (o < 18) {
            outf[((size_t)(b * 18 + o) * H + hy) * W + hx] = vv + pA[o];
          } else if (o < 27) {
            const float z = vv + pA[o];
            out1[((size_t)(b * 9 + (o - 18)) * H + hy) * W + hx] = 2.f / (1.f + expf(-z));
          }
        } else if constexpr (MODE == 1) {
          const size_t oi = ((size_t)(b * C + o) * H + hy) * W + hx;
          const float a = pA[o];
          outh[oi] = f2bf(vv > 0.f ? vv : a * vv);
        } else {
          const size_t oi = ((size_t)(b * C + o) * H + hy) * W + hx;
          const float s  = pA[o] * rsqrtf(pV[o] + 1e-5f);
          const float sh = pB[o] - pM[o] * s;
          outf[oi] = vv * s + sh + resid[oi];
        }
      }
    }
  }
}

__global__ void xcvt(const float* __restrict__ x, unsigned short* __restrict__ xb)
{
  const int i = blockIdx.x * 256 + threadIdx.x;
  const float4 v = ((const float4*)x)[i];
  ushort4 o;
  o.x = f2bf(v.x); o.y = f2bf(v.y); o.z = f2bf(v.z); o.w = f2bf(v.w);
  *(ushort4*)(xb + (size_t)i * 4) = o;
}

// Emit lane-swizzled weights: wS[ch][ot][lane][j] = wLogical[o][kp],
// o = ot*16 + (lane&15), kp = ch*32 + (lane>>4)*8 + j.
// kp<1152: chn=kp>>5 -> cg=chn/9, tap=chn%9, c=cg*32+(kp&31).
// kp in [1152,1161): BN-shift column (layer-1 only).
__global__ void prep3(const float* __restrict__ w1, const float* __restrict__ w2,
                      const float* __restrict__ ow1, const float* __restrict__ mw1,
                      const float* __restrict__ ob1, const float* __restrict__ mb1,
                      const float* __restrict__ ow2, const float* __restrict__ mw2,
                      const float* __restrict__ ob2, const float* __restrict__ mb2,
                      const float* __restrict__ g, const float* __restrict__ bb,
                      const float* __restrict__ m, const float* __restrict__ v,
                      unsigned short* __restrict__ wb1, unsigned short* __restrict__ wb2,
                      unsigned short* __restrict__ wom1, unsigned short* __restrict__ wom2,
                      float* __restrict__ bias1, float* __restrict__ bias2)
{
  const int i = blockIdx.x * 256 + threadIdx.x;
  if (i < 128 * KT2) {              // deform weights, O=128, NT=8
    const int lane = (i >> 3) & 63, ot = (i >> 9) & 7, ch = i >> 12;
    const int o  = ot * 16 + (lane & 15);
    const int kp = ch * 32 + ((lane >> 4) << 3) + (i & 7);
    unsigned short v1 = 0, v2 = 0;
    if (kp < 1152) {
      const int chn = kp >> 5, jj = kp & 31;
      const int cg = chn / 9, tap = chn - 9 * cg;
      const int c = (cg << 5) + jj;
      const float s = g[c] * rsqrtf(v[c] + 1e-5f);
      v1 = f2bf(w1[(size_t)(o * 128 + c) * 9 + tap] * s);
      v2 = f2bf(w2[(size_t)(o * 128 + c) * 9 + tap]);
    } else if (kp < 1152 + KK) {
      const int kk = kp - 1152;
      float acc = 0.f;
      for (int c = 0; c < 128; ++c) {
        const float s  = g[c] * rsqrtf(v[c] + 1e-5f);
        const float sh = bb[c] - m[c] * s;
        acc += w1[(size_t)(o * 128 + c) * 9 + kk] * sh;
      }
      v1 = f2bf(acc);
    }
    wb1[i] = v1; wb2[i] = v2;
  }
  if (i < 32 * KT2) {               // offset/mask weights, O=32, NT=2
    const int lane = (i >> 3) & 63, ot = (i >> 9) & 1, ch = i >> 10;
    const int o  = ot * 16 + (lane & 15);
    const int kp = ch * 32 + ((lane >> 4) << 3) + (i & 7);
    unsigned short v1 = 0, v2 = 0;
    if (kp < 1152) {
      const int chn = kp >> 5, jj = kp & 31;
      const int cg = chn / 9, tap = chn - 9 * cg;
      const int c = (cg << 5) + jj;
      const float s = g[c] * rsqrtf(v[c] + 1e-5f);
      if (o < 18) {
        v1 = f2bf(ow1[(size_t)(o * 128 + c) * 9 + tap] * s);
        v2 = f2bf(ow2[(size_t)(o * 128 + c) * 9 + tap]);
      } else if (o < 27) {
        v1 = f2bf(mw1[(size_t)((o - 18) * 128 + c) * 9 + tap] * s);
        v2 = f2bf(mw2[(size_t)((o - 18) * 128 + c) * 9 + tap]);
      }
    } else if (kp < 1152 + KK && o < 27) {
      const int kk = kp - 1152;
      const float* wsrc = (o < 18) ? ow1 + (size_t)o * 1152
                                   : mw1 + (size_t)(o - 18) * 1152;
      float acc = 0.f;
      for (int c = 0; c < 128; ++c) {
        const float s  = g[c] * rsqrtf(v[c] + 1e-5f);
        const float sh = bb[c] - m[c] * s;
        acc += wsrc[(size_t)c * 9 + kk] * sh;
      }
      v1 = f2bf(acc);
    }
    wom1[i] = v1; wom2[i] = v2;
  }
  if (i < 32) {
    float b1 = 0.f, b2 = 0.f;
    if (i < 18)      { b1 = ob1[i];      b2 = ob2[i]; }
    else if (i < 27) { b1 = mb1[i - 18]; b2 = mb2[i - 18]; }
    bias1[i] = b1; bias2[i] = b2;
  }
}

extern "C" void kernel_launch(void* const* d_in, const int* in_sizes, int n_in,
                              void* d_out, int out_size, void* d_ws, size_t ws_size,
                              hipStream_t stream)
{
  const float* x     = (const float*)d_in[0];
  const float* bn1g  = (const float*)d_in[1];
  const float* bn1b  = (const float*)d_in[2];
  const float* bn1m  = (const float*)d_in[3];
  const float* bn1v  = (const float*)d_in[4];
  const float* ow1   = (const float*)d_in[5];
  const float* ob1   = (const float*)d_in[6];
  const float* mw1   = (const float*)d_in[7];
  const float* mb1   = (const float*)d_in[8];
  const float* w1    = (const float*)d_in[9];
  const float* alpha = (const float*)d_in[10];
  const float* ow2   = (const float*)d_in[11];
  const float* ob2   = (const float*)d_in[12];
  const float* mw2   = (const float*)d_in[13];
  const float* mb2   = (const float*)d_in[14];
  const float* w2    = (const float*)d_in[15];
  const float* bn2g  = (const float*)d_in[16];
  const float* bn2b  = (const float*)d_in[17];
  const float* bn2m  = (const float*)d_in[18];
  const float* bn2v  = (const float*)d_in[19];
  float* out = (float*)d_out;

  char* wsp = (char*)d_ws;
  unsigned short* xbf  = (unsigned short*)(wsp);             // 16777216 B
  unsigned short* r2bf = (unsigned short*)(wsp + 16777216);  // 16777216 B
  float* offb = (float*)(wsp + 33554432);                    // 4718592 B
  float* mskb = (float*)(wsp + 38273024);                    // 2359296 B
  unsigned short* wb1  = (unsigned short*)(wsp + 40632320);  // 303104 B
  unsigned short* wb2  = (unsigned short*)(wsp + 40935424);  // 303104 B
  unsigned short* wom1 = (unsigned short*)(wsp + 41238528);  // 75776 B
  unsigned short* wom2 = (unsigned short*)(wsp + 41314304);  // 75776 B
  float* bias1 = (float*)(wsp + 41390080);
  float* bias2 = (float*)(wsp + 41390208);

  xcvt<<<8192, 256, 0, stream>>>(x, xbf);
  prep3<<<(128 * KT2 + 255) / 256, 256, 0, stream>>>(
      w1, w2, ow1, mw1, ob1, mb1, ow2, mw2, ob2, mb2,
      bn1g, bn1b, bn1m, bn1v, wb1, wb2, wom1, wom2, bias1, bias2);

  dim3 grid(4096);
  dim3 blk(256);
  gemm5<0, true><<<grid, blk, 0, stream>>>(xbf, wom1, nullptr, nullptr, bias1,
      nullptr, nullptr, nullptr, nullptr, offb, nullptr, mskb);
  gemm5<1, true><<<grid, blk, 0, stream>>>(xbf, wb1, offb, mskb, alpha,
      nullptr, nullptr, nullptr, nullptr, nullptr, r2bf, nullptr);
  gemm5<0, false><<<grid, blk, 0, stream>>>(r2bf, wom2, nullptr, nullptr, bias2,
      nullptr, nullptr, nullptr, nullptr, offb, nullptr, mskb);
  gemm5<2, false><<<grid, blk, 0, stream>>>(r2bf, wb2, offb, mskb, bn2g,
      bn2b, bn2m, bn2v, x, out, nullptr, nullptr);
}